// Round 5
// baseline (121.144 us; speedup 1.0000x reference)
//
#include <hip/hip_runtime.h>
#include <math.h>

typedef float f32x4 __attribute__((ext_vector_type(4)));
typedef short bf16x8 __attribute__((ext_vector_type(8)));

#define N_LBL 128
#define TS 128
#define MAXG 128

constexpr float T_INV = 2.0f;   // 1/T, T=0.5
constexpr float EPSf  = 1e-8f;

__device__ inline float wave_reduce_sum64(float v) {
#pragma unroll
  for (int m = 32; m >= 1; m >>= 1) v += __shfl_xor(v, m, 64);
  return v;
}

__device__ inline unsigned short f2bf(float f) {  // RNE
  unsigned int u = __float_as_uint(f);
  unsigned int r = (u + 0x7FFFu + ((u >> 16) & 1u)) >> 16;
  return (unsigned short)r;
}

// Fused setup. Blocks 0..n-1: row inverse-norm + bf16 convert + D zero.
// Block n: label histogram -> scan -> scatter (single block, overlapped).
__global__ __launch_bounds__(256) void k_prep(const float* __restrict__ x,
    const int* __restrict__ y, float* __restrict__ invn, float* __restrict__ D,
    unsigned short* __restrict__ xb, float* __restrict__ accum, int* __restrict__ done,
    int* __restrict__ offs_g, int* __restrict__ rows, int* __restrict__ rank,
    int n, int d) {
  int row = blockIdx.x;
  int t = threadIdx.x;

  if (row == n) {  // ---- label machinery block ----
    __shared__ int hist[N_LBL];
    __shared__ int curs[N_LBL];
    __shared__ int loffs[N_LBL + 1];
    if (t < N_LBL) { hist[t] = 0; curs[t] = 0; }
    __syncthreads();
    for (int i = t; i < n; i += 256) atomicAdd(&hist[y[i]], 1);
    __syncthreads();
    if (t == 0) {
      int acc = 0;
      for (int l = 0; l < N_LBL; ++l) { loffs[l] = acc; acc += hist[l]; }
      loffs[N_LBL] = acc;
    }
    __syncthreads();
    if (t <= N_LBL) offs_g[t] = loffs[t];
    for (int i = t; i < n; i += 256) {
      int g = y[i];
      int pos = atomicAdd(&curs[g], 1);
      rows[loffs[g] + pos] = i;
      rank[i] = pos;
    }
    return;
  }

  const float4* xr = (const float4*)(x + (size_t)row * d);
  float ss = 0.f;
  for (int i = t; i < d / 4; i += 256) {
    float4 v = xr[i];
    ss += v.x * v.x + v.y * v.y + v.z * v.z + v.w * v.w;
    if (xb) {
      ushort4 h;
      h.x = f2bf(v.x); h.y = f2bf(v.y); h.z = f2bf(v.z); h.w = f2bf(v.w);
      *(ushort4*)(xb + (size_t)row * d + i * 4) = h;
    }
  }
  __shared__ float part[4];
  ss = wave_reduce_sum64(ss);
  int lane = t & 63, wid = t >> 6;
  if (lane == 0) part[wid] = ss;
  __syncthreads();
  if (t == 0) {
    float tot = part[0] + part[1] + part[2] + part[3];
    invn[row] = 1.0f / fmaxf(sqrtf(tot), EPSf);
    D[row] = 0.f;
    if (row == 0) { *accum = 0.f; *done = 0; }
  }
}

// ---------------- Gram pass, fast path: 2-phase dbuf global_load_lds ------
// LDS panel: 128 rows x 64 bf16 (128 B/row); physical 16B chunk p of row r
// holds logical chunk p ^ (r&7) (XOR applied on the per-lane GLOBAL source;
// LDS dest linear, as global_load_lds requires). Two buffers: STAGE(t+1)
// issued BEFORE compute(t); single __syncthreads (vmcnt(0) drain) per step.
__global__ __launch_bounds__(256) void k_gram_ldsdma(
    const unsigned short* __restrict__ xb, const float* __restrict__ invn,
    const int* __restrict__ y, const int* __restrict__ rank,
    float* __restrict__ D, float* __restrict__ S, int n, int d, int nb) {
  // bijective XCD-chunked remap (m204)
  int nwg = nb * (nb + 1) / 2;
  int q8 = nwg >> 3, r8 = nwg & 7;
  int xcd = blockIdx.x & 7, ridx = blockIdx.x >> 3;
  int bid = (xcd < r8 ? xcd * (q8 + 1) : r8 * (q8 + 1) + (xcd - r8) * q8) + ridx;

  // triangular decode: bid -> (by, bx) with by <= bx
  int by = 0, rowlen = nb, rem = bid;
  while (rem >= rowlen) { rem -= rowlen; ++by; --rowlen; }
  int bx = by + rem;
  int rowBase = by * TS, colBase = bx * TS;
  bool diag = (bx == by);

  __shared__ char lds[2][2][16384];   // [buf][A/B][128 rows x 128 B]
  __shared__ float ir_s[128], ic_s[128];
  __shared__ int yr_s[128], yc_s[128];
  __shared__ int rr_s[128], rc_s[128];

  int t = threadIdx.x;
  int lane = t & 63, wid = t >> 6;
  int wr = wid >> 1, wc = wid & 1;          // 2x2 wave grid, 64x64 per wave
  int l15 = lane & 15, l4 = lane >> 4;
  int lrow = lane >> 3, lp = lane & 7;      // staging: row-in-segment / chunk

  if (t < 128) {
    ir_s[t] = invn[rowBase + t]; yr_s[t] = y[rowBase + t]; rr_s[t] = rank[rowBase + t];
    ic_s[t] = invn[colBase + t]; yc_s[t] = y[colBase + t]; rc_s[t] = rank[colBase + t];
  }

  f32x4 acc[4][4];
#pragma unroll
  for (int m = 0; m < 4; ++m)
#pragma unroll
    for (int nn = 0; nn < 4; ++nn) acc[m][nn] = (f32x4){0.f, 0.f, 0.f, 0.f};

#define STAGE(gstep, buf)                                                     \
  do {                                                                        \
    _Pragma("unroll")                                                         \
    for (int j = 0; j < 4; ++j) {                                             \
      int seg = wid * 4 + j;                                                  \
      int row = seg * 8 + lrow;                                               \
      const unsigned short* srcA = xb + (size_t)(rowBase + row) * d           \
                                   + (gstep) * 64 + ((lp ^ (row & 7)) << 3);  \
      __builtin_amdgcn_global_load_lds(                                       \
          (const __attribute__((address_space(1))) void*)srcA,               \
          (__attribute__((address_space(3))) void*)(&lds[buf][0][seg * 1024]),\
          16, 0, 0);                                                          \
    }                                                                         \
    if (!diag) {                                                              \
      _Pragma("unroll")                                                       \
      for (int j = 0; j < 4; ++j) {                                           \
        int seg = wid * 4 + j;                                                \
        int row = seg * 8 + lrow;                                             \
        const unsigned short* srcB = xb + (size_t)(colBase + row) * d         \
                                     + (gstep) * 64 + ((lp ^ (row & 7)) << 3);\
        __builtin_amdgcn_global_load_lds(                                     \
            (const __attribute__((address_space(1))) void*)srcB,             \
            (__attribute__((address_space(3))) void*)(&lds[buf][1][seg * 1024]),\
            16, 0, 0);                                                        \
      }                                                                       \
    }                                                                         \
  } while (0)

  int nt = d / 64;
  STAGE(0, 0);
  __syncthreads();   // tile 0 resident

  for (int g = 0; g < nt; ++g) {
    int cur = g & 1;
    if (g + 1 < nt) STAGE(g + 1, cur ^ 1);   // loads fly under the MFMAs below

    const char* ldsA = &lds[cur][0][0];
    const char* ldsBr = diag ? ldsA : &lds[cur][1][0];
#pragma unroll
    for (int kk = 0; kk < 2; ++kk) {
      bf16x8 a[4], b[4];
#pragma unroll
      for (int m = 0; m < 4; ++m) {
        int row = wr * 64 + m * 16 + l15;
        int slot = (kk * 4 + l4) ^ (row & 7);
        a[m] = *(const bf16x8*)(ldsA + row * 128 + slot * 16);
      }
#pragma unroll
      for (int nn = 0; nn < 4; ++nn) {
        int row = wc * 64 + nn * 16 + l15;
        int slot = (kk * 4 + l4) ^ (row & 7);
        b[nn] = *(const bf16x8*)(ldsBr + row * 128 + slot * 16);
      }
#pragma unroll
      for (int m = 0; m < 4; ++m)
#pragma unroll
        for (int nn = 0; nn < 4; ++nn)
          acc[m][nn] = __builtin_amdgcn_mfma_f32_16x16x32_bf16(a[m], b[nn], acc[m][nn], 0, 0, 0);
    }
    __syncthreads();   // drains vmcnt(0): next tile ready; cur safe to overwrite
  }
#undef STAGE

  // epilogue: C/D frag layout col=lane&15, row=(lane>>4)*4+r
  float cs[4] = {0.f, 0.f, 0.f, 0.f};
#pragma unroll
  for (int m = 0; m < 4; ++m) {
#pragma unroll
    for (int r = 0; r < 4; ++r) {
      int lr = wr * 64 + m * 16 + l4 * 4 + r;
      int gi = rowBase + lr;
      float ivr = ir_s[lr];
      int yi = yr_s[lr];
      float rs = 0.f;
#pragma unroll
      for (int nn = 0; nn < 4; ++nn) {
        int lc = wc * 64 + nn * 16 + l15;
        int gj = colBase + lc;
        float sim = acc[m][nn][r] * ivr * ic_s[lc];
        sim = fminf(fmaxf(sim, -1.0f + EPSf), 1.0f - EPSf);
        float s = fminf(__expf(sim * T_INV), 1e10f);
        if (yc_s[lc] != yi) {
          rs += s; cs[nn] += s;
        } else if (gi != gj) {
          S[(size_t)gi * MAXG + rc_s[lc]] = s;
          if (!diag) S[(size_t)gj * MAXG + rr_s[lr]] = s;
        }
      }
      rs += __shfl_xor(rs, 1, 64);
      rs += __shfl_xor(rs, 2, 64);
      rs += __shfl_xor(rs, 4, 64);
      rs += __shfl_xor(rs, 8, 64);
      if (l15 == 0) atomicAdd(&D[rowBase + lr], rs);
    }
  }
  if (!diag) {
#pragma unroll
    for (int nn = 0; nn < 4; ++nn) {
      float v = cs[nn];
      v += __shfl_xor(v, 16, 64);
      v += __shfl_xor(v, 32, 64);
      if (l4 == 0) atomicAdd(&D[colBase + wc * 64 + nn * 16 + l15], v);
    }
  }
}

// ---------------- Gram pass, fallback: reg-staged f32->bf16 ---------------
__global__ __launch_bounds__(256) void k_gram_reg(const float* __restrict__ x,
    const float* __restrict__ invn, const int* __restrict__ y,
    const int* __restrict__ rank, float* __restrict__ D, float* __restrict__ S,
    int n, int d, int nb) {
  int bid = blockIdx.x;
  int by = 0, rowlen = nb, rem = bid;
  while (rem >= rowlen) { rem -= rowlen; ++by; --rowlen; }
  int bx = by + rem;
  int rowBase = by * TS, colBase = bx * TS;
  bool diag = (bx == by);

  __shared__ char ldsA[128 * 128];
  __shared__ char ldsB[128 * 128];
  __shared__ float ir_s[128], ic_s[128];
  __shared__ int yr_s[128], yc_s[128];
  __shared__ int rr_s[128], rc_s[128];

  int t = threadIdx.x;
  int lane = t & 63, wid = t >> 6;
  int wr = wid >> 1, wc = wid & 1;
  int l15 = lane & 15, l4 = lane >> 4;

  if (t < 128) {
    ir_s[t] = invn[rowBase + t]; yr_s[t] = y[rowBase + t]; rr_s[t] = rank[rowBase + t];
    ic_s[t] = invn[colBase + t]; yc_s[t] = y[colBase + t]; rc_s[t] = rank[colBase + t];
  }

  f32x4 acc[4][4];
#pragma unroll
  for (int m = 0; m < 4; ++m)
#pragma unroll
    for (int nn = 0; nn < 4; ++nn) acc[m][nn] = (f32x4){0.f, 0.f, 0.f, 0.f};

  const char* ldsBr = diag ? ldsA : ldsB;

  for (int k0 = 0; k0 < d; k0 += 64) {
    __syncthreads();
#pragma unroll
    for (int i = 0; i < 8; ++i) {
      int c = t + i * 256;
      int row = c >> 4, fc = c & 15;
      float4 v = *(const float4*)(x + (size_t)(rowBase + row) * d + k0 + fc * 4);
      ushort4 h;
      h.x = f2bf(v.x); h.y = f2bf(v.y); h.z = f2bf(v.z); h.w = f2bf(v.w);
      int off = row * 128 + ((((fc >> 1) ^ (row & 7))) << 4) + (fc & 1) * 8;
      *(ushort4*)(ldsA + off) = h;
    }
    if (!diag) {
#pragma unroll
      for (int i = 0; i < 8; ++i) {
        int c = t + i * 256;
        int row = c >> 4, fc = c & 15;
        float4 v = *(const float4*)(x + (size_t)(colBase + row) * d + k0 + fc * 4);
        ushort4 h;
        h.x = f2bf(v.x); h.y = f2bf(v.y); h.z = f2bf(v.z); h.w = f2bf(v.w);
        int off = row * 128 + ((((fc >> 1) ^ (row & 7))) << 4) + (fc & 1) * 8;
        *(ushort4*)(ldsB + off) = h;
      }
    }
    __syncthreads();

#pragma unroll
    for (int kk = 0; kk < 2; ++kk) {
      bf16x8 a[4], b[4];
#pragma unroll
      for (int m = 0; m < 4; ++m) {
        int row = wr * 64 + m * 16 + l15;
        int slot = (kk * 4 + l4) ^ (row & 7);
        a[m] = *(const bf16x8*)(ldsA + row * 128 + slot * 16);
      }
#pragma unroll
      for (int nn = 0; nn < 4; ++nn) {
        int row = wc * 64 + nn * 16 + l15;
        int slot = (kk * 4 + l4) ^ (row & 7);
        b[nn] = *(const bf16x8*)(ldsBr + row * 128 + slot * 16);
      }
#pragma unroll
      for (int m = 0; m < 4; ++m)
#pragma unroll
        for (int nn = 0; nn < 4; ++nn)
          acc[m][nn] = __builtin_amdgcn_mfma_f32_16x16x32_bf16(a[m], b[nn], acc[m][nn], 0, 0, 0);
    }
  }

  float cs[4] = {0.f, 0.f, 0.f, 0.f};
#pragma unroll
  for (int m = 0; m < 4; ++m) {
#pragma unroll
    for (int r = 0; r < 4; ++r) {
      int lr = wr * 64 + m * 16 + l4 * 4 + r;
      int gi = rowBase + lr;
      float ivr = ir_s[lr];
      int yi = yr_s[lr];
      float rs = 0.f;
#pragma unroll
      for (int nn = 0; nn < 4; ++nn) {
        int lc = wc * 64 + nn * 16 + l15;
        int gj = colBase + lc;
        float sim = acc[m][nn][r] * ivr * ic_s[lc];
        sim = fminf(fmaxf(sim, -1.0f + EPSf), 1.0f - EPSf);
        float s = fminf(__expf(sim * T_INV), 1e10f);
        if (yc_s[lc] != yi) {
          rs += s; cs[nn] += s;
        } else if (S && gi != gj) {
          S[(size_t)gi * MAXG + rc_s[lc]] = s;
          if (!diag) S[(size_t)gj * MAXG + rr_s[lr]] = s;
        }
      }
      rs += __shfl_xor(rs, 1, 64);
      rs += __shfl_xor(rs, 2, 64);
      rs += __shfl_xor(rs, 4, 64);
      rs += __shfl_xor(rs, 8, 64);
      if (l15 == 0) atomicAdd(&D[rowBase + lr], rs);
    }
  }
  if (!diag) {
#pragma unroll
    for (int nn = 0; nn < 4; ++nn) {
      float v = cs[nn];
      v += __shfl_xor(v, 16, 64);
      v += __shfl_xor(v, 32, 64);
      if (l4 == 0) atomicAdd(&D[colBase + wc * 64 + nn * 16 + l15], v);
    }
  }
}

// Pass B (fast): read persisted same-label s values; fused final reduce.
__global__ __launch_bounds__(256) void k_loss2(const int* __restrict__ y,
    const int* __restrict__ offs, const int* __restrict__ rows,
    const float* __restrict__ D, const float* __restrict__ S,
    float* __restrict__ accum, int* __restrict__ done,
    float* __restrict__ out, int out_size, int n) {
  int gid = blockIdx.x * blockDim.x + threadIdx.x;
  int i = gid >> 7;          // MAXG = 128
  int slot = gid & (MAXG - 1);
  float term = 0.f;
  if (i < n) {
    int g = y[i];
    int start = offs[g], cnt = offs[g + 1] - start;
    if (slot < cnt) {
      int j = rows[start + slot];
      if (j != i) {
        float s = S[(size_t)i * MAXG + slot];
        term = logf(s + D[i] + EPSf) - logf(s);
      }
    }
  }
  term = wave_reduce_sum64(term);
  __shared__ float part[4];
  int lane = threadIdx.x & 63, wid = threadIdx.x >> 6;
  if (lane == 0) part[wid] = term;
  __syncthreads();
  if (threadIdx.x == 0) {
    atomicAdd(accum, part[0] + part[1] + part[2] + part[3]);
    __threadfence();
    int ticket = atomicAdd(done, 1);
    if (ticket == (int)gridDim.x - 1) {
      __threadfence();
      float v = *(volatile float*)accum;
      for (int k = 0; k < out_size; ++k) out[k] = v / (2.0f * n);
    }
  }
}

// Pass B (fallback): recompute dots for same-label pairs
__global__ __launch_bounds__(256) void k_loss(const float* __restrict__ x,
    const float* __restrict__ invn, const int* __restrict__ y,
    const int* __restrict__ offs, const int* __restrict__ rows,
    const float* __restrict__ D, float* __restrict__ accum, int n, int d) {
  int i = blockIdx.x;
  int t = threadIdx.x, lane = t & 63, wid = t >> 6;
  __shared__ float4 xi4[256];
  __shared__ float wpart[4];

  const float4* xr = (const float4*)(x + (size_t)i * d);
  for (int q = t; q < d / 4; q += 256) xi4[q] = xr[q];
  __syncthreads();

  int g = y[i];
  int start = offs[g], end = offs[g + 1];
  float invi = invn[i];
  float Di = D[i];
  float wsum = 0.f;

  for (int idx = start + wid; idx < end; idx += 4) {
    int j = rows[idx];
    if (j == i) continue;
    const float4* xj = (const float4*)(x + (size_t)j * d);
    float acc = 0.f;
#pragma unroll 4
    for (int q = 0; q < d / 256; ++q) {
      float4 vj = xj[lane + 64 * q];
      float4 vi = xi4[lane + 64 * q];
      acc = fmaf(vj.x, vi.x, acc);
      acc = fmaf(vj.y, vi.y, acc);
      acc = fmaf(vj.z, vi.z, acc);
      acc = fmaf(vj.w, vi.w, acc);
    }
    acc = wave_reduce_sum64(acc);
    if (lane == 0) {
      float sim = acc * invi * invn[j];
      sim = fminf(fmaxf(sim, -1.0f + EPSf), 1.0f - EPSf);
      float s = fminf(expf(sim * T_INV), 1e10f);
      wsum += logf(s + Di + EPSf) - logf(s);
    }
  }

  if (lane == 0) wpart[wid] = wsum;
  __syncthreads();
  if (t == 0) atomicAdd(accum, wpart[0] + wpart[1] + wpart[2] + wpart[3]);
}

__global__ void k_final(const float* __restrict__ accum, float* __restrict__ out,
    int out_size, int n) {
  int i = blockIdx.x * blockDim.x + threadIdx.x;
  if (i < out_size) out[i] = *accum / (2.0f * n);
}

extern "C" void kernel_launch(void* const* d_in, const int* in_sizes, int n_in,
                              void* d_out, int out_size, void* d_ws, size_t ws_size,
                              hipStream_t stream) {
  const float* x = (const float*)d_in[0];
  const int*   y = (const int*)d_in[1];
  int n = in_sizes[1];
  int d = in_sizes[0] / n;

  char* ws = (char*)d_ws;
  float* invn  = (float*)(ws);            // 16 KB
  float* D     = (float*)(ws + 16384);    // 16 KB
  int*   offs  = (int*)(ws + 32768);      // 129 ints (pad to 2 KB)
  int*   rows  = (int*)(ws + 34816);      // 16 KB
  int*   rank  = (int*)(ws + 51200);      // 16 KB
  float* accum = (float*)(ws + 67584);    // 4 B
  int*   done  = (int*)(ws + 67588);      // 4 B (pad to 1 KB total)
  float* S     = (float*)(ws + 68608);    // n*MAXG*4 = 2 MB
  size_t xb_off = 68608 + (size_t)n * MAXG * 4;
  xb_off = (xb_off + 255) & ~(size_t)255;
  unsigned short* xb = (unsigned short*)(ws + xb_off);

  bool hasS  = ws_size >= 68608 + (size_t)n * MAXG * 4;
  bool hasXb = hasS && ws_size >= xb_off + (size_t)n * d * 2;

  k_prep<<<n + 1, 256, 0, stream>>>(x, y, invn, D, hasXb ? xb : nullptr,
                                    accum, done, offs, rows, rank, n, d);

  int nb = n / TS;
  int nblocks = nb * (nb + 1) / 2;
  if (hasXb) {
    k_gram_ldsdma<<<nblocks, 256, 0, stream>>>(xb, invn, y, rank, D, S, n, d, nb);
  } else {
    k_gram_reg<<<nblocks, 256, 0, stream>>>(x, invn, y, rank, D, hasS ? S : nullptr, n, d, nb);
  }
  if (hasS) {
    int lblocks = (n * MAXG + 255) / 256;
    k_loss2<<<lblocks, 256, 0, stream>>>(y, offs, rows, D, S, accum, done,
                                         (float*)d_out, out_size, n);
  } else {
    k_loss<<<n, 256, 0, stream>>>(x, invn, y, offs, rows, D, accum, n, d);
    k_final<<<1, 64, 0, stream>>>(accum, (float*)d_out, out_size, n);
  }
}

// Round 6
// 74.262 us; speedup vs baseline: 1.6313x; 1.6313x over previous
//
#include <hip/hip_runtime.h>
#include <math.h>

typedef float f32x4 __attribute__((ext_vector_type(4)));
typedef short bf16x8 __attribute__((ext_vector_type(8)));

#define N_LBL 128
#define TS 128
#define MAXG 128
#define LBLK 512

constexpr float T_INV = 2.0f;   // 1/T, T=0.5
constexpr float EPSf  = 1e-8f;

__device__ inline float wave_reduce_sum64(float v) {
#pragma unroll
  for (int m = 32; m >= 1; m >>= 1) v += __shfl_xor(v, m, 64);
  return v;
}

__device__ inline unsigned short f2bf(float f) {  // RNE
  unsigned int u = __float_as_uint(f);
  unsigned int r = (u + 0x7FFFu + ((u >> 16) & 1u)) >> 16;
  return (unsigned short)r;
}

// Fused setup. Blocks 0..n-1: row inverse-norm + bf16 convert + D zero.
// Block n: label histogram -> scan -> scatter (single block, overlapped).
__global__ __launch_bounds__(256) void k_prep(const float* __restrict__ x,
    const int* __restrict__ y, float* __restrict__ invn, float* __restrict__ D,
    unsigned short* __restrict__ xb, float* __restrict__ accum,
    int* __restrict__ offs_g, int* __restrict__ rows, int* __restrict__ rank,
    int n, int d) {
  int row = blockIdx.x;
  int t = threadIdx.x;

  if (row == n) {  // ---- label machinery block ----
    __shared__ int hist[N_LBL];
    __shared__ int curs[N_LBL];
    __shared__ int loffs[N_LBL + 1];
    if (t < N_LBL) { hist[t] = 0; curs[t] = 0; }
    __syncthreads();
    for (int i = t; i < n; i += 256) atomicAdd(&hist[y[i]], 1);
    __syncthreads();
    if (t == 0) {
      int acc = 0;
      for (int l = 0; l < N_LBL; ++l) { loffs[l] = acc; acc += hist[l]; }
      loffs[N_LBL] = acc;
    }
    __syncthreads();
    if (t <= N_LBL) offs_g[t] = loffs[t];
    for (int i = t; i < n; i += 256) {
      int g = y[i];
      int pos = atomicAdd(&curs[g], 1);
      rows[loffs[g] + pos] = i;
      rank[i] = pos;
    }
    return;
  }

  const float4* xr = (const float4*)(x + (size_t)row * d);
  float ss = 0.f;
  for (int i = t; i < d / 4; i += 256) {
    float4 v = xr[i];
    ss += v.x * v.x + v.y * v.y + v.z * v.z + v.w * v.w;
    if (xb) {
      ushort4 h;
      h.x = f2bf(v.x); h.y = f2bf(v.y); h.z = f2bf(v.z); h.w = f2bf(v.w);
      *(ushort4*)(xb + (size_t)row * d + i * 4) = h;
    }
  }
  __shared__ float part[4];
  ss = wave_reduce_sum64(ss);
  int lane = t & 63, wid = t >> 6;
  if (lane == 0) part[wid] = ss;
  __syncthreads();
  if (t == 0) {
    float tot = part[0] + part[1] + part[2] + part[3];
    invn[row] = 1.0f / fmaxf(sqrtf(tot), EPSf);
    D[row] = 0.f;
    if (row == 0) *accum = 0.f;
  }
}

// ---------------- Gram pass, fast path: 2-phase dbuf global_load_lds ------
// LDS panel: 128 rows x 64 bf16 (128 B/row); physical 16B chunk p of row r
// holds logical chunk p ^ (r&7) (XOR applied on the per-lane GLOBAL source;
// LDS dest linear, as global_load_lds requires). Two buffers: STAGE(t+1)
// issued BEFORE compute(t); single __syncthreads (vmcnt(0) drain) per step.
__global__ __launch_bounds__(256) void k_gram_ldsdma(
    const unsigned short* __restrict__ xb, const float* __restrict__ invn,
    const int* __restrict__ y, const int* __restrict__ rank,
    float* __restrict__ D, float* __restrict__ S, int n, int d, int nb) {
  // bijective XCD-chunked remap (m204)
  int nwg = nb * (nb + 1) / 2;
  int q8 = nwg >> 3, r8 = nwg & 7;
  int xcd = blockIdx.x & 7, ridx = blockIdx.x >> 3;
  int bid = (xcd < r8 ? xcd * (q8 + 1) : r8 * (q8 + 1) + (xcd - r8) * q8) + ridx;

  // triangular decode: bid -> (by, bx) with by <= bx
  int by = 0, rowlen = nb, rem = bid;
  while (rem >= rowlen) { rem -= rowlen; ++by; --rowlen; }
  int bx = by + rem;
  int rowBase = by * TS, colBase = bx * TS;
  bool diag = (bx == by);

  __shared__ char lds[2][2][16384];   // [buf][A/B][128 rows x 128 B]
  __shared__ float ir_s[128], ic_s[128];
  __shared__ int yr_s[128], yc_s[128];
  __shared__ int rr_s[128], rc_s[128];

  int t = threadIdx.x;
  int lane = t & 63, wid = t >> 6;
  int wr = wid >> 1, wc = wid & 1;          // 2x2 wave grid, 64x64 per wave
  int l15 = lane & 15, l4 = lane >> 4;
  int lrow = lane >> 3, lp = lane & 7;      // staging: row-in-segment / chunk

  if (t < 128) {
    ir_s[t] = invn[rowBase + t]; yr_s[t] = y[rowBase + t]; rr_s[t] = rank[rowBase + t];
    ic_s[t] = invn[colBase + t]; yc_s[t] = y[colBase + t]; rc_s[t] = rank[colBase + t];
  }

  f32x4 acc[4][4];
#pragma unroll
  for (int m = 0; m < 4; ++m)
#pragma unroll
    for (int nn = 0; nn < 4; ++nn) acc[m][nn] = (f32x4){0.f, 0.f, 0.f, 0.f};

#define STAGE(gstep, buf)                                                     \
  do {                                                                        \
    _Pragma("unroll")                                                         \
    for (int j = 0; j < 4; ++j) {                                             \
      int seg = wid * 4 + j;                                                  \
      int row = seg * 8 + lrow;                                               \
      const unsigned short* srcA = xb + (size_t)(rowBase + row) * d           \
                                   + (gstep) * 64 + ((lp ^ (row & 7)) << 3);  \
      __builtin_amdgcn_global_load_lds(                                       \
          (const __attribute__((address_space(1))) void*)srcA,               \
          (__attribute__((address_space(3))) void*)(&lds[buf][0][seg * 1024]),\
          16, 0, 0);                                                          \
    }                                                                         \
    if (!diag) {                                                              \
      _Pragma("unroll")                                                       \
      for (int j = 0; j < 4; ++j) {                                           \
        int seg = wid * 4 + j;                                                \
        int row = seg * 8 + lrow;                                             \
        const unsigned short* srcB = xb + (size_t)(colBase + row) * d         \
                                     + (gstep) * 64 + ((lp ^ (row & 7)) << 3);\
        __builtin_amdgcn_global_load_lds(                                     \
            (const __attribute__((address_space(1))) void*)srcB,             \
            (__attribute__((address_space(3))) void*)(&lds[buf][1][seg * 1024]),\
            16, 0, 0);                                                        \
      }                                                                       \
    }                                                                         \
  } while (0)

  int nt = d / 64;
  STAGE(0, 0);
  __syncthreads();   // tile 0 resident

  for (int g = 0; g < nt; ++g) {
    int cur = g & 1;
    if (g + 1 < nt) STAGE(g + 1, cur ^ 1);   // loads fly under the MFMAs below

    const char* ldsA = &lds[cur][0][0];
    const char* ldsBr = diag ? ldsA : &lds[cur][1][0];
#pragma unroll
    for (int kk = 0; kk < 2; ++kk) {
      bf16x8 a[4], b[4];
#pragma unroll
      for (int m = 0; m < 4; ++m) {
        int row = wr * 64 + m * 16 + l15;
        int slot = (kk * 4 + l4) ^ (row & 7);
        a[m] = *(const bf16x8*)(ldsA + row * 128 + slot * 16);
      }
#pragma unroll
      for (int nn = 0; nn < 4; ++nn) {
        int row = wc * 64 + nn * 16 + l15;
        int slot = (kk * 4 + l4) ^ (row & 7);
        b[nn] = *(const bf16x8*)(ldsBr + row * 128 + slot * 16);
      }
#pragma unroll
      for (int m = 0; m < 4; ++m)
#pragma unroll
        for (int nn = 0; nn < 4; ++nn)
          acc[m][nn] = __builtin_amdgcn_mfma_f32_16x16x32_bf16(a[m], b[nn], acc[m][nn], 0, 0, 0);
    }
    __syncthreads();   // drains vmcnt(0): next tile ready; cur safe to overwrite
  }
#undef STAGE

  // epilogue: C/D frag layout col=lane&15, row=(lane>>4)*4+r
  float cs[4] = {0.f, 0.f, 0.f, 0.f};
#pragma unroll
  for (int m = 0; m < 4; ++m) {
#pragma unroll
    for (int r = 0; r < 4; ++r) {
      int lr = wr * 64 + m * 16 + l4 * 4 + r;
      int gi = rowBase + lr;
      float ivr = ir_s[lr];
      int yi = yr_s[lr];
      float rs = 0.f;
#pragma unroll
      for (int nn = 0; nn < 4; ++nn) {
        int lc = wc * 64 + nn * 16 + l15;
        int gj = colBase + lc;
        float sim = acc[m][nn][r] * ivr * ic_s[lc];
        sim = fminf(fmaxf(sim, -1.0f + EPSf), 1.0f - EPSf);
        float s = fminf(__expf(sim * T_INV), 1e10f);
        if (yc_s[lc] != yi) {
          rs += s; cs[nn] += s;
        } else if (gi != gj) {
          S[(size_t)gi * MAXG + rc_s[lc]] = s;
          if (!diag) S[(size_t)gj * MAXG + rr_s[lr]] = s;
        }
      }
      rs += __shfl_xor(rs, 1, 64);
      rs += __shfl_xor(rs, 2, 64);
      rs += __shfl_xor(rs, 4, 64);
      rs += __shfl_xor(rs, 8, 64);
      if (l15 == 0) atomicAdd(&D[rowBase + lr], rs);
    }
  }
  if (!diag) {
#pragma unroll
    for (int nn = 0; nn < 4; ++nn) {
      float v = cs[nn];
      v += __shfl_xor(v, 16, 64);
      v += __shfl_xor(v, 32, 64);
      if (l4 == 0) atomicAdd(&D[colBase + wc * 64 + nn * 16 + l15], v);
    }
  }
}

// ---------------- Gram pass, fallback: reg-staged f32->bf16 ---------------
__global__ __launch_bounds__(256) void k_gram_reg(const float* __restrict__ x,
    const float* __restrict__ invn, const int* __restrict__ y,
    const int* __restrict__ rank, float* __restrict__ D, float* __restrict__ S,
    int n, int d, int nb) {
  int bid = blockIdx.x;
  int by = 0, rowlen = nb, rem = bid;
  while (rem >= rowlen) { rem -= rowlen; ++by; --rowlen; }
  int bx = by + rem;
  int rowBase = by * TS, colBase = bx * TS;
  bool diag = (bx == by);

  __shared__ char ldsA[128 * 128];
  __shared__ char ldsB[128 * 128];
  __shared__ float ir_s[128], ic_s[128];
  __shared__ int yr_s[128], yc_s[128];
  __shared__ int rr_s[128], rc_s[128];

  int t = threadIdx.x;
  int lane = t & 63, wid = t >> 6;
  int wr = wid >> 1, wc = wid & 1;
  int l15 = lane & 15, l4 = lane >> 4;

  if (t < 128) {
    ir_s[t] = invn[rowBase + t]; yr_s[t] = y[rowBase + t]; rr_s[t] = rank[rowBase + t];
    ic_s[t] = invn[colBase + t]; yc_s[t] = y[colBase + t]; rc_s[t] = rank[colBase + t];
  }

  f32x4 acc[4][4];
#pragma unroll
  for (int m = 0; m < 4; ++m)
#pragma unroll
    for (int nn = 0; nn < 4; ++nn) acc[m][nn] = (f32x4){0.f, 0.f, 0.f, 0.f};

  const char* ldsBr = diag ? ldsA : ldsB;

  for (int k0 = 0; k0 < d; k0 += 64) {
    __syncthreads();
#pragma unroll
    for (int i = 0; i < 8; ++i) {
      int c = t + i * 256;
      int row = c >> 4, fc = c & 15;
      float4 v = *(const float4*)(x + (size_t)(rowBase + row) * d + k0 + fc * 4);
      ushort4 h;
      h.x = f2bf(v.x); h.y = f2bf(v.y); h.z = f2bf(v.z); h.w = f2bf(v.w);
      int off = row * 128 + ((((fc >> 1) ^ (row & 7))) << 4) + (fc & 1) * 8;
      *(ushort4*)(ldsA + off) = h;
    }
    if (!diag) {
#pragma unroll
      for (int i = 0; i < 8; ++i) {
        int c = t + i * 256;
        int row = c >> 4, fc = c & 15;
        float4 v = *(const float4*)(x + (size_t)(colBase + row) * d + k0 + fc * 4);
        ushort4 h;
        h.x = f2bf(v.x); h.y = f2bf(v.y); h.z = f2bf(v.z); h.w = f2bf(v.w);
        int off = row * 128 + ((((fc >> 1) ^ (row & 7))) << 4) + (fc & 1) * 8;
        *(ushort4*)(ldsB + off) = h;
      }
    }
    __syncthreads();

#pragma unroll
    for (int kk = 0; kk < 2; ++kk) {
      bf16x8 a[4], b[4];
#pragma unroll
      for (int m = 0; m < 4; ++m) {
        int row = wr * 64 + m * 16 + l15;
        int slot = (kk * 4 + l4) ^ (row & 7);
        a[m] = *(const bf16x8*)(ldsA + row * 128 + slot * 16);
      }
#pragma unroll
      for (int nn = 0; nn < 4; ++nn) {
        int row = wc * 64 + nn * 16 + l15;
        int slot = (kk * 4 + l4) ^ (row & 7);
        b[nn] = *(const bf16x8*)(ldsBr + row * 128 + slot * 16);
      }
#pragma unroll
      for (int m = 0; m < 4; ++m)
#pragma unroll
        for (int nn = 0; nn < 4; ++nn)
          acc[m][nn] = __builtin_amdgcn_mfma_f32_16x16x32_bf16(a[m], b[nn], acc[m][nn], 0, 0, 0);
    }
  }

  float cs[4] = {0.f, 0.f, 0.f, 0.f};
#pragma unroll
  for (int m = 0; m < 4; ++m) {
#pragma unroll
    for (int r = 0; r < 4; ++r) {
      int lr = wr * 64 + m * 16 + l4 * 4 + r;
      int gi = rowBase + lr;
      float ivr = ir_s[lr];
      int yi = yr_s[lr];
      float rs = 0.f;
#pragma unroll
      for (int nn = 0; nn < 4; ++nn) {
        int lc = wc * 64 + nn * 16 + l15;
        int gj = colBase + lc;
        float sim = acc[m][nn][r] * ivr * ic_s[lc];
        sim = fminf(fmaxf(sim, -1.0f + EPSf), 1.0f - EPSf);
        float s = fminf(__expf(sim * T_INV), 1e10f);
        if (yc_s[lc] != yi) {
          rs += s; cs[nn] += s;
        } else if (S && gi != gj) {
          S[(size_t)gi * MAXG + rc_s[lc]] = s;
          if (!diag) S[(size_t)gj * MAXG + rr_s[lr]] = s;
        }
      }
      rs += __shfl_xor(rs, 1, 64);
      rs += __shfl_xor(rs, 2, 64);
      rs += __shfl_xor(rs, 4, 64);
      rs += __shfl_xor(rs, 8, 64);
      if (l15 == 0) atomicAdd(&D[rowBase + lr], rs);
    }
  }
  if (!diag) {
#pragma unroll
    for (int nn = 0; nn < 4; ++nn) {
      float v = cs[nn];
      v += __shfl_xor(v, 16, 64);
      v += __shfl_xor(v, 32, 64);
      if (l4 == 0) atomicAdd(&D[colBase + wc * 64 + nn * 16 + l15], v);
    }
  }
}

// Pass B (fast): grid-strided; per-block partial sums, no global atomics.
__global__ __launch_bounds__(256) void k_loss2(const int* __restrict__ y,
    const int* __restrict__ offs, const int* __restrict__ rows,
    const float* __restrict__ D, const float* __restrict__ S,
    float* __restrict__ partials, int n) {
  int t = threadIdx.x;
  int total = n * MAXG;
  float sum = 0.f;
  for (int gid = blockIdx.x * 256 + t; gid < total; gid += gridDim.x * 256) {
    int i = gid >> 7;          // MAXG = 128
    int slot = gid & (MAXG - 1);
    int g = y[i];
    int start = offs[g], cnt = offs[g + 1] - start;
    if (slot < cnt) {
      int j = rows[start + slot];
      if (j != i) {
        float s = S[(size_t)i * MAXG + slot];
        sum += logf(s + D[i] + EPSf) - logf(s);
      }
    }
  }
  sum = wave_reduce_sum64(sum);
  __shared__ float part[4];
  int lane = t & 63, wid = t >> 6;
  if (lane == 0) part[wid] = sum;
  __syncthreads();
  if (t == 0) partials[blockIdx.x] = part[0] + part[1] + part[2] + part[3];
}

// Pass B (fallback): recompute dots for same-label pairs
__global__ __launch_bounds__(256) void k_loss(const float* __restrict__ x,
    const float* __restrict__ invn, const int* __restrict__ y,
    const int* __restrict__ offs, const int* __restrict__ rows,
    const float* __restrict__ D, float* __restrict__ accum, int n, int d) {
  int i = blockIdx.x;
  int t = threadIdx.x, lane = t & 63, wid = t >> 6;
  __shared__ float4 xi4[256];
  __shared__ float wpart[4];

  const float4* xr = (const float4*)(x + (size_t)i * d);
  for (int q = t; q < d / 4; q += 256) xi4[q] = xr[q];
  __syncthreads();

  int g = y[i];
  int start = offs[g], end = offs[g + 1];
  float invi = invn[i];
  float Di = D[i];
  float wsum = 0.f;

  for (int idx = start + wid; idx < end; idx += 4) {
    int j = rows[idx];
    if (j == i) continue;
    const float4* xj = (const float4*)(x + (size_t)j * d);
    float acc = 0.f;
#pragma unroll 4
    for (int q = 0; q < d / 256; ++q) {
      float4 vj = xj[lane + 64 * q];
      float4 vi = xi4[lane + 64 * q];
      acc = fmaf(vj.x, vi.x, acc);
      acc = fmaf(vj.y, vi.y, acc);
      acc = fmaf(vj.z, vi.z, acc);
      acc = fmaf(vj.w, vi.w, acc);
    }
    acc = wave_reduce_sum64(acc);
    if (lane == 0) {
      float sim = acc * invi * invn[j];
      sim = fminf(fmaxf(sim, -1.0f + EPSf), 1.0f - EPSf);
      float s = fminf(expf(sim * T_INV), 1e10f);
      wsum += logf(s + Di + EPSf) - logf(s);
    }
  }

  if (lane == 0) wpart[wid] = wsum;
  __syncthreads();
  if (t == 0) atomicAdd(accum, wpart[0] + wpart[1] + wpart[2] + wpart[3]);
}

// Final reduce: sums `cnt` partials, writes out/(2n).
__global__ __launch_bounds__(256) void k_final(const float* __restrict__ partials,
    int cnt, float* __restrict__ out, int out_size, int n) {
  int t = threadIdx.x;
  float s = 0.f;
  for (int i = t; i < cnt; i += 256) s += partials[i];
  s = wave_reduce_sum64(s);
  __shared__ float part[4];
  int lane = t & 63, wid = t >> 6;
  if (lane == 0) part[wid] = s;
  __syncthreads();
  if (t == 0) {
    float v = part[0] + part[1] + part[2] + part[3];
    for (int k = 0; k < out_size; ++k) out[k] = v / (2.0f * n);
  }
}

extern "C" void kernel_launch(void* const* d_in, const int* in_sizes, int n_in,
                              void* d_out, int out_size, void* d_ws, size_t ws_size,
                              hipStream_t stream) {
  const float* x = (const float*)d_in[0];
  const int*   y = (const int*)d_in[1];
  int n = in_sizes[1];
  int d = in_sizes[0] / n;

  char* ws = (char*)d_ws;
  float* invn     = (float*)(ws);            // 16 KB
  float* D        = (float*)(ws + 16384);    // 16 KB
  int*   offs     = (int*)(ws + 32768);      // 129 ints (pad to 2 KB)
  int*   rows     = (int*)(ws + 34816);      // 16 KB
  int*   rank     = (int*)(ws + 51200);      // 16 KB
  float* accum    = (float*)(ws + 67584);    // 4 B (pad 256 B)
  float* partials = (float*)(ws + 67840);    // LBLK floats (2 KB)
  float* S        = (float*)(ws + 69888);    // n*MAXG*4 = 2 MB
  size_t xb_off = 69888 + (size_t)n * MAXG * 4;
  xb_off = (xb_off + 255) & ~(size_t)255;
  unsigned short* xb = (unsigned short*)(ws + xb_off);

  bool hasS  = ws_size >= 69888 + (size_t)n * MAXG * 4;
  bool hasXb = hasS && ws_size >= xb_off + (size_t)n * d * 2;

  k_prep<<<n + 1, 256, 0, stream>>>(x, y, invn, D, hasXb ? xb : nullptr,
                                    accum, offs, rows, rank, n, d);

  int nb = n / TS;
  int nblocks = nb * (nb + 1) / 2;
  if (hasXb) {
    k_gram_ldsdma<<<nblocks, 256, 0, stream>>>(xb, invn, y, rank, D, S, n, d, nb);
  } else {
    k_gram_reg<<<nblocks, 256, 0, stream>>>(x, invn, y, rank, D, hasS ? S : nullptr, n, d, nb);
  }
  if (hasS) {
    k_loss2<<<LBLK, 256, 0, stream>>>(y, offs, rows, D, S, partials, n);
    k_final<<<1, 256, 0, stream>>>(partials, LBLK, (float*)d_out, out_size, n);
  } else {
    k_loss<<<n, 256, 0, stream>>>(x, invn, y, offs, rows, D, accum, n, d);
    k_final<<<1, 256, 0, stream>>>(accum, 1, (float*)d_out, out_size, n);
  }
}

// Round 7
// 73.001 us; speedup vs baseline: 1.6595x; 1.0173x over previous
//
#include <hip/hip_runtime.h>
#include <math.h>

typedef float f32x4 __attribute__((ext_vector_type(4)));
typedef short bf16x8 __attribute__((ext_vector_type(8)));

#define N_LBL 128
#define TS 128
#define MAXG 128
#define LBLK 512

constexpr float T_INV = 2.0f;   // 1/T, T=0.5
constexpr float EPSf  = 1e-8f;

__device__ inline float wave_reduce_sum64(float v) {
#pragma unroll
  for (int m = 32; m >= 1; m >>= 1) v += __shfl_xor(v, m, 64);
  return v;
}

__device__ inline unsigned short f2bf(float f) {  // RNE
  unsigned int u = __float_as_uint(f);
  unsigned int r = (u + 0x7FFFu + ((u >> 16) & 1u)) >> 16;
  return (unsigned short)r;
}

// Fused setup. Blocks 0..n-1: row inverse-norm + bf16 convert + D zero.
// Block n: label histogram -> scan -> scatter (single block, overlapped).
__global__ __launch_bounds__(256) void k_prep(const float* __restrict__ x,
    const int* __restrict__ y, float* __restrict__ invn, float* __restrict__ D,
    unsigned short* __restrict__ xb, float* __restrict__ accum,
    int* __restrict__ offs_g, int* __restrict__ rows, int* __restrict__ rank,
    int n, int d) {
  int row = blockIdx.x;
  int t = threadIdx.x;

  if (row == n) {  // ---- label machinery block ----
    __shared__ int hist[N_LBL];
    __shared__ int curs[N_LBL];
    __shared__ int loffs[N_LBL + 1];
    if (t < N_LBL) { hist[t] = 0; curs[t] = 0; }
    __syncthreads();
    for (int i = t; i < n; i += 256) atomicAdd(&hist[y[i]], 1);
    __syncthreads();
    if (t == 0) {
      int acc = 0;
      for (int l = 0; l < N_LBL; ++l) { loffs[l] = acc; acc += hist[l]; }
      loffs[N_LBL] = acc;
    }
    __syncthreads();
    if (t <= N_LBL) offs_g[t] = loffs[t];
    for (int i = t; i < n; i += 256) {
      int g = y[i];
      int pos = atomicAdd(&curs[g], 1);
      rows[loffs[g] + pos] = i;
      rank[i] = pos;
    }
    return;
  }

  const float4* xr = (const float4*)(x + (size_t)row * d);
  float ss = 0.f;
  for (int i = t; i < d / 4; i += 256) {
    float4 v = xr[i];
    ss += v.x * v.x + v.y * v.y + v.z * v.z + v.w * v.w;
    if (xb) {
      ushort4 h;
      h.x = f2bf(v.x); h.y = f2bf(v.y); h.z = f2bf(v.z); h.w = f2bf(v.w);
      *(ushort4*)(xb + (size_t)row * d + i * 4) = h;
    }
  }
  __shared__ float part[4];
  ss = wave_reduce_sum64(ss);
  int lane = t & 63, wid = t >> 6;
  if (lane == 0) part[wid] = ss;
  __syncthreads();
  if (t == 0) {
    float tot = part[0] + part[1] + part[2] + part[3];
    invn[row] = 1.0f / fmaxf(sqrtf(tot), EPSf);
    D[row] = 0.f;
    if (row == 0) *accum = 0.f;
  }
}

// ---------------- Gram pass, fast path ------------------------------------
// 512 threads (8 waves, 2x4 wave grid; wave tile 64x32), 128^2 block tile,
// BK=128 (8 K-steps), SINGLE-buffered global_load_lds staging.
// LDS panel: 128 rows x 128 bf16 (256 B/row). Physical 16B chunk p of row r
// holds logical chunk p ^ (r&7) (XOR applied on the per-lane GLOBAL source
// address; LDS dest stays linear, as global_load_lds requires).
__global__ __launch_bounds__(512) void k_gram_ldsdma(
    const unsigned short* __restrict__ xb, const float* __restrict__ invn,
    const int* __restrict__ y, const int* __restrict__ rank,
    float* __restrict__ D, float* __restrict__ S, int n, int d, int nb) {
  // bijective XCD-chunked remap (m204)
  int nwg = nb * (nb + 1) / 2;
  int q8 = nwg >> 3, r8 = nwg & 7;
  int xcd = blockIdx.x & 7, ridx = blockIdx.x >> 3;
  int bid = (xcd < r8 ? xcd * (q8 + 1) : r8 * (q8 + 1) + (xcd - r8) * q8) + ridx;

  // triangular decode: bid -> (by, bx) with by <= bx
  int by = 0, rowlen = nb, rem = bid;
  while (rem >= rowlen) { rem -= rowlen; ++by; --rowlen; }
  int bx = by + rem;
  int rowBase = by * TS, colBase = bx * TS;
  bool diag = (bx == by);

  __shared__ char ldsA[128 * 256];   // 32 KB
  __shared__ char ldsB[128 * 256];   // 32 KB
  __shared__ float ir_s[128], ic_s[128];
  __shared__ int yr_s[128], yc_s[128];
  __shared__ int rr_s[128], rc_s[128];

  int t = threadIdx.x;
  int lane = t & 63, wid = t >> 6;
  int wr = wid >> 2, wc = wid & 3;          // 2x4 wave grid, 64x32 per wave
  int l15 = lane & 15, l4 = lane >> 4;
  int lrow = lane >> 4, lp = lane & 15;     // staging: row-in-4 / chunk 0..15

  if (t < 128) {
    ir_s[t] = invn[rowBase + t]; yr_s[t] = y[rowBase + t]; rr_s[t] = rank[rowBase + t];
    ic_s[t] = invn[colBase + t]; yc_s[t] = y[colBase + t]; rc_s[t] = rank[colBase + t];
  }

  f32x4 acc[4][2];
#pragma unroll
  for (int m = 0; m < 4; ++m)
#pragma unroll
    for (int nn = 0; nn < 2; ++nn) acc[m][nn] = (f32x4){0.f, 0.f, 0.f, 0.f};

  const char* ldsBr = diag ? ldsA : ldsB;
  int nt = d / 128;     // 8 K-steps

  for (int g = 0; g < nt; ++g) {
    __syncthreads();    // prev compute done: safe to overwrite panels
    // stage A: 128 rows x 256 B; each wave-instr writes 1 KB = 4 rows.
    // seg = 4-row group (0..31): seg = wid*4 + j.
#pragma unroll
    for (int j = 0; j < 4; ++j) {
      int seg = wid * 4 + j;
      int row = seg * 4 + lrow;
      const unsigned short* srcA = xb + (size_t)(rowBase + row) * d + g * 128
                                   + ((lp ^ (row & 7)) << 3);
      __builtin_amdgcn_global_load_lds(
          (const __attribute__((address_space(1))) void*)srcA,
          (__attribute__((address_space(3))) void*)(ldsA + seg * 1024), 16, 0, 0);
    }
    if (!diag) {
#pragma unroll
      for (int j = 0; j < 4; ++j) {
        int seg = wid * 4 + j;
        int row = seg * 4 + lrow;
        const unsigned short* srcB = xb + (size_t)(colBase + row) * d + g * 128
                                     + ((lp ^ (row & 7)) << 3);
        __builtin_amdgcn_global_load_lds(
            (const __attribute__((address_space(1))) void*)srcB,
            (__attribute__((address_space(3))) void*)(ldsB + seg * 1024), 16, 0, 0);
      }
    }
    __syncthreads();    // drain: tile resident

#pragma unroll
    for (int kk = 0; kk < 4; ++kk) {
      bf16x8 a[4], b[2];
#pragma unroll
      for (int m = 0; m < 4; ++m) {
        int row = wr * 64 + m * 16 + l15;
        int slot = (kk * 4 + l4) ^ (row & 7);
        a[m] = *(const bf16x8*)(ldsA + row * 256 + slot * 16);
      }
#pragma unroll
      for (int nn = 0; nn < 2; ++nn) {
        int row = wc * 32 + nn * 16 + l15;
        int slot = (kk * 4 + l4) ^ (row & 7);
        b[nn] = *(const bf16x8*)(ldsBr + row * 256 + slot * 16);
      }
#pragma unroll
      for (int m = 0; m < 4; ++m)
#pragma unroll
        for (int nn = 0; nn < 2; ++nn)
          acc[m][nn] = __builtin_amdgcn_mfma_f32_16x16x32_bf16(a[m], b[nn], acc[m][nn], 0, 0, 0);
    }
  }

  // epilogue: C/D frag layout col=lane&15, row=(lane>>4)*4+r
  float cs[2] = {0.f, 0.f};
#pragma unroll
  for (int m = 0; m < 4; ++m) {
#pragma unroll
    for (int r = 0; r < 4; ++r) {
      int lr = wr * 64 + m * 16 + l4 * 4 + r;
      int gi = rowBase + lr;
      float ivr = ir_s[lr];
      int yi = yr_s[lr];
      float rs = 0.f;
#pragma unroll
      for (int nn = 0; nn < 2; ++nn) {
        int lc = wc * 32 + nn * 16 + l15;
        int gj = colBase + lc;
        float sim = acc[m][nn][r] * ivr * ic_s[lc];
        sim = fminf(fmaxf(sim, -1.0f + EPSf), 1.0f - EPSf);
        float s = fminf(__expf(sim * T_INV), 1e10f);
        if (yc_s[lc] != yi) {
          rs += s; cs[nn] += s;
        } else if (gi != gj) {
          S[(size_t)gi * MAXG + rc_s[lc]] = s;
          if (!diag) S[(size_t)gj * MAXG + rr_s[lr]] = s;
        }
      }
      rs += __shfl_xor(rs, 1, 64);
      rs += __shfl_xor(rs, 2, 64);
      rs += __shfl_xor(rs, 4, 64);
      rs += __shfl_xor(rs, 8, 64);
      if (l15 == 0) atomicAdd(&D[rowBase + lr], rs);
    }
  }
  if (!diag) {
#pragma unroll
    for (int nn = 0; nn < 2; ++nn) {
      float v = cs[nn];
      v += __shfl_xor(v, 16, 64);
      v += __shfl_xor(v, 32, 64);
      if (l4 == 0) atomicAdd(&D[colBase + wc * 32 + nn * 16 + l15], v);
    }
  }
}

// ---------------- Gram pass, fallback: reg-staged f32->bf16 ---------------
__global__ __launch_bounds__(256) void k_gram_reg(const float* __restrict__ x,
    const float* __restrict__ invn, const int* __restrict__ y,
    const int* __restrict__ rank, float* __restrict__ D, float* __restrict__ S,
    int n, int d, int nb) {
  int bid = blockIdx.x;
  int by = 0, rowlen = nb, rem = bid;
  while (rem >= rowlen) { rem -= rowlen; ++by; --rowlen; }
  int bx = by + rem;
  int rowBase = by * TS, colBase = bx * TS;
  bool diag = (bx == by);

  __shared__ char ldsA[128 * 128];
  __shared__ char ldsB[128 * 128];
  __shared__ float ir_s[128], ic_s[128];
  __shared__ int yr_s[128], yc_s[128];
  __shared__ int rr_s[128], rc_s[128];

  int t = threadIdx.x;
  int lane = t & 63, wid = t >> 6;
  int wr = wid >> 1, wc = wid & 1;
  int l15 = lane & 15, l4 = lane >> 4;

  if (t < 128) {
    ir_s[t] = invn[rowBase + t]; yr_s[t] = y[rowBase + t]; rr_s[t] = rank[rowBase + t];
    ic_s[t] = invn[colBase + t]; yc_s[t] = y[colBase + t]; rc_s[t] = rank[colBase + t];
  }

  f32x4 acc[4][4];
#pragma unroll
  for (int m = 0; m < 4; ++m)
#pragma unroll
    for (int nn = 0; nn < 4; ++nn) acc[m][nn] = (f32x4){0.f, 0.f, 0.f, 0.f};

  const char* ldsBr = diag ? ldsA : ldsB;

  for (int k0 = 0; k0 < d; k0 += 64) {
    __syncthreads();
#pragma unroll
    for (int i = 0; i < 8; ++i) {
      int c = t + i * 256;
      int row = c >> 4, fc = c & 15;
      float4 v = *(const float4*)(x + (size_t)(rowBase + row) * d + k0 + fc * 4);
      ushort4 h;
      h.x = f2bf(v.x); h.y = f2bf(v.y); h.z = f2bf(v.z); h.w = f2bf(v.w);
      int off = row * 128 + ((((fc >> 1) ^ (row & 7))) << 4) + (fc & 1) * 8;
      *(ushort4*)(ldsA + off) = h;
    }
    if (!diag) {
#pragma unroll
      for (int i = 0; i < 8; ++i) {
        int c = t + i * 256;
        int row = c >> 4, fc = c & 15;
        float4 v = *(const float4*)(x + (size_t)(colBase + row) * d + k0 + fc * 4);
        ushort4 h;
        h.x = f2bf(v.x); h.y = f2bf(v.y); h.z = f2bf(v.z); h.w = f2bf(v.w);
        int off = row * 128 + ((((fc >> 1) ^ (row & 7))) << 4) + (fc & 1) * 8;
        *(ushort4*)(ldsB + off) = h;
      }
    }
    __syncthreads();

#pragma unroll
    for (int kk = 0; kk < 2; ++kk) {
      bf16x8 a[4], b[4];
#pragma unroll
      for (int m = 0; m < 4; ++m) {
        int row = wr * 64 + m * 16 + l15;
        int slot = (kk * 4 + l4) ^ (row & 7);
        a[m] = *(const bf16x8*)(ldsA + row * 128 + slot * 16);
      }
#pragma unroll
      for (int nn = 0; nn < 4; ++nn) {
        int row = wc * 64 + nn * 16 + l15;
        int slot = (kk * 4 + l4) ^ (row & 7);
        b[nn] = *(const bf16x8*)(ldsBr + row * 128 + slot * 16);
      }
#pragma unroll
      for (int m = 0; m < 4; ++m)
#pragma unroll
        for (int nn = 0; nn < 4; ++nn)
          acc[m][nn] = __builtin_amdgcn_mfma_f32_16x16x32_bf16(a[m], b[nn], acc[m][nn], 0, 0, 0);
    }
  }

  float cs[4] = {0.f, 0.f, 0.f, 0.f};
#pragma unroll
  for (int m = 0; m < 4; ++m) {
#pragma unroll
    for (int r = 0; r < 4; ++r) {
      int lr = wr * 64 + m * 16 + l4 * 4 + r;
      int gi = rowBase + lr;
      float ivr = ir_s[lr];
      int yi = yr_s[lr];
      float rs = 0.f;
#pragma unroll
      for (int nn = 0; nn < 4; ++nn) {
        int lc = wc * 64 + nn * 16 + l15;
        int gj = colBase + lc;
        float sim = acc[m][nn][r] * ivr * ic_s[lc];
        sim = fminf(fmaxf(sim, -1.0f + EPSf), 1.0f - EPSf);
        float s = fminf(__expf(sim * T_INV), 1e10f);
        if (yc_s[lc] != yi) {
          rs += s; cs[nn] += s;
        } else if (S && gi != gj) {
          S[(size_t)gi * MAXG + rc_s[lc]] = s;
          if (!diag) S[(size_t)gj * MAXG + rr_s[lr]] = s;
        }
      }
      rs += __shfl_xor(rs, 1, 64);
      rs += __shfl_xor(rs, 2, 64);
      rs += __shfl_xor(rs, 4, 64);
      rs += __shfl_xor(rs, 8, 64);
      if (l15 == 0) atomicAdd(&D[rowBase + lr], rs);
    }
  }
  if (!diag) {
#pragma unroll
    for (int nn = 0; nn < 4; ++nn) {
      float v = cs[nn];
      v += __shfl_xor(v, 16, 64);
      v += __shfl_xor(v, 32, 64);
      if (l4 == 0) atomicAdd(&D[colBase + wc * 64 + nn * 16 + l15], v);
    }
  }
}

// Pass B (fast): grid-strided; per-block partial sums, no global atomics.
__global__ __launch_bounds__(256) void k_loss2(const int* __restrict__ y,
    const int* __restrict__ offs, const int* __restrict__ rows,
    const float* __restrict__ D, const float* __restrict__ S,
    float* __restrict__ partials, int n) {
  int t = threadIdx.x;
  int total = n * MAXG;
  float sum = 0.f;
  for (int gid = blockIdx.x * 256 + t; gid < total; gid += gridDim.x * 256) {
    int i = gid >> 7;          // MAXG = 128
    int slot = gid & (MAXG - 1);
    int g = y[i];
    int start = offs[g], cnt = offs[g + 1] - start;
    if (slot < cnt) {
      int j = rows[start + slot];
      if (j != i) {
        float s = S[(size_t)i * MAXG + slot];
        sum += logf(s + D[i] + EPSf) - logf(s);
      }
    }
  }
  sum = wave_reduce_sum64(sum);
  __shared__ float part[4];
  int lane = t & 63, wid = t >> 6;
  if (lane == 0) part[wid] = sum;
  __syncthreads();
  if (t == 0) partials[blockIdx.x] = part[0] + part[1] + part[2] + part[3];
}

// Pass B (fallback): recompute dots for same-label pairs
__global__ __launch_bounds__(256) void k_loss(const float* __restrict__ x,
    const float* __restrict__ invn, const int* __restrict__ y,
    const int* __restrict__ offs, const int* __restrict__ rows,
    const float* __restrict__ D, float* __restrict__ accum, int n, int d) {
  int i = blockIdx.x;
  int t = threadIdx.x, lane = t & 63, wid = t >> 6;
  __shared__ float4 xi4[256];
  __shared__ float wpart[4];

  const float4* xr = (const float4*)(x + (size_t)i * d);
  for (int q = t; q < d / 4; q += 256) xi4[q] = xr[q];
  __syncthreads();

  int g = y[i];
  int start = offs[g], end = offs[g + 1];
  float invi = invn[i];
  float Di = D[i];
  float wsum = 0.f;

  for (int idx = start + wid; idx < end; idx += 4) {
    int j = rows[idx];
    if (j == i) continue;
    const float4* xj = (const float4*)(x + (size_t)j * d);
    float acc = 0.f;
#pragma unroll 4
    for (int q = 0; q < d / 256; ++q) {
      float4 vj = xj[lane + 64 * q];
      float4 vi = xi4[lane + 64 * q];
      acc = fmaf(vj.x, vi.x, acc);
      acc = fmaf(vj.y, vi.y, acc);
      acc = fmaf(vj.z, vi.z, acc);
      acc = fmaf(vj.w, vi.w, acc);
    }
    acc = wave_reduce_sum64(acc);
    if (lane == 0) {
      float sim = acc * invi * invn[j];
      sim = fminf(fmaxf(sim, -1.0f + EPSf), 1.0f - EPSf);
      float s = fminf(expf(sim * T_INV), 1e10f);
      wsum += logf(s + Di + EPSf) - logf(s);
    }
  }

  if (lane == 0) wpart[wid] = wsum;
  __syncthreads();
  if (t == 0) atomicAdd(accum, wpart[0] + wpart[1] + wpart[2] + wpart[3]);
}

// Final reduce: sums `cnt` partials, writes out/(2n).
__global__ __launch_bounds__(256) void k_final(const float* __restrict__ partials,
    int cnt, float* __restrict__ out, int out_size, int n) {
  int t = threadIdx.x;
  float s = 0.f;
  for (int i = t; i < cnt; i += 256) s += partials[i];
  s = wave_reduce_sum64(s);
  __shared__ float part[4];
  int lane = t & 63, wid = t >> 6;
  if (lane == 0) part[wid] = s;
  __syncthreads();
  if (t == 0) {
    float v = part[0] + part[1] + part[2] + part[3];
    for (int k = 0; k < out_size; ++k) out[k] = v / (2.0f * n);
  }
}

extern "C" void kernel_launch(void* const* d_in, const int* in_sizes, int n_in,
                              void* d_out, int out_size, void* d_ws, size_t ws_size,
                              hipStream_t stream) {
  const float* x = (const float*)d_in[0];
  const int*   y = (const int*)d_in[1];
  int n = in_sizes[1];
  int d = in_sizes[0] / n;

  char* ws = (char*)d_ws;
  float* invn     = (float*)(ws);            // 16 KB
  float* D        = (float*)(ws + 16384);    // 16 KB
  int*   offs     = (int*)(ws + 32768);      // 129 ints (pad to 2 KB)
  int*   rows     = (int*)(ws + 34816);      // 16 KB
  int*   rank     = (int*)(ws + 51200);      // 16 KB
  float* accum    = (float*)(ws + 67584);    // 4 B (pad 256 B)
  float* partials = (float*)(ws + 67840);    // LBLK floats (2 KB)
  float* S        = (float*)(ws + 69888);    // n*MAXG*4 = 2 MB
  size_t xb_off = 69888 + (size_t)n * MAXG * 4;
  xb_off = (xb_off + 255) & ~(size_t)255;
  unsigned short* xb = (unsigned short*)(ws + xb_off);

  bool hasS  = ws_size >= 69888 + (size_t)n * MAXG * 4;
  bool hasXb = hasS && ws_size >= xb_off + (size_t)n * d * 2 && (d % 128 == 0);

  k_prep<<<n + 1, 256, 0, stream>>>(x, y, invn, D, hasXb ? xb : nullptr,
                                    accum, offs, rows, rank, n, d);

  int nb = n / TS;
  int nblocks = nb * (nb + 1) / 2;
  if (hasXb) {
    k_gram_ldsdma<<<nblocks, 512, 0, stream>>>(xb, invn, y, rank, D, S, n, d, nb);
  } else {
    k_gram_reg<<<nblocks, 256, 0, stream>>>(x, invn, y, rank, D, hasS ? S : nullptr, n, d, nb);
  }
  if (hasS) {
    k_loss2<<<LBLK, 256, 0, stream>>>(y, offs, rows, D, S, partials, n);
    k_final<<<1, 256, 0, stream>>>(partials, LBLK, (float*)d_out, out_size, n);
  } else {
    k_loss<<<n, 256, 0, stream>>>(x, invn, y, offs, rows, D, accum, n, d);
    k_final<<<1, 256, 0, stream>>>(accum, 1, (float*)d_out, out_size, n);
  }
}

// Round 8
// 54.943 us; speedup vs baseline: 2.2049x; 1.3287x over previous
//
#include <hip/hip_runtime.h>
#include <math.h>

typedef float f32x4 __attribute__((ext_vector_type(4)));
typedef short bf16x8 __attribute__((ext_vector_type(8)));

#define N_LBL 128
#define TS 128
#define MAXG 128
#define LBLK 512

constexpr float T_INV = 2.0f;   // 1/T, T=0.5
constexpr float EPSf  = 1e-8f;

__device__ inline float wave_reduce_sum64(float v) {
#pragma unroll
  for (int m = 32; m >= 1; m >>= 1) v += __shfl_xor(v, m, 64);
  return v;
}

__device__ inline unsigned short f2bf(float f) {  // RNE
  unsigned int u = __float_as_uint(f);
  unsigned int r = (u + 0x7FFFu + ((u >> 16) & 1u)) >> 16;
  return (unsigned short)r;
}

// Fused setup. Blocks 0..n-1: row inverse-norm + fp8 convert + D zero.
// Block n: label histogram -> scan -> scatter (single block, overlapped).
__global__ __launch_bounds__(256) void k_prep(const float* __restrict__ x,
    const int* __restrict__ y, float* __restrict__ invn, float* __restrict__ D,
    unsigned char* __restrict__ xb, float* __restrict__ accum,
    int* __restrict__ offs_g, int* __restrict__ rows, int* __restrict__ rank,
    int n, int d) {
  int row = blockIdx.x;
  int t = threadIdx.x;

  if (row == n) {  // ---- label machinery block ----
    __shared__ int hist[N_LBL];
    __shared__ int curs[N_LBL];
    __shared__ int loffs[N_LBL + 1];
    if (t < N_LBL) { hist[t] = 0; curs[t] = 0; }
    __syncthreads();
    for (int i = t; i < n; i += 256) atomicAdd(&hist[y[i]], 1);
    __syncthreads();
    if (t == 0) {
      int acc = 0;
      for (int l = 0; l < N_LBL; ++l) { loffs[l] = acc; acc += hist[l]; }
      loffs[N_LBL] = acc;
    }
    __syncthreads();
    if (t <= N_LBL) offs_g[t] = loffs[t];
    for (int i = t; i < n; i += 256) {
      int g = y[i];
      int pos = atomicAdd(&curs[g], 1);
      rows[loffs[g] + pos] = i;
      rank[i] = pos;
    }
    return;
  }

  const float4* xr = (const float4*)(x + (size_t)row * d);
  float ss = 0.f;
  for (int i = t; i < d / 4; i += 256) {
    float4 v = xr[i];
    ss += v.x * v.x + v.y * v.y + v.z * v.z + v.w * v.w;
    if (xb) {
      int p = __builtin_amdgcn_cvt_pk_fp8_f32(v.x, v.y, 0, false);
      p = __builtin_amdgcn_cvt_pk_fp8_f32(v.z, v.w, p, true);
      *(unsigned int*)(xb + (size_t)row * d + i * 4) = (unsigned int)p;
    }
  }
  __shared__ float part[4];
  ss = wave_reduce_sum64(ss);
  int lane = t & 63, wid = t >> 6;
  if (lane == 0) part[wid] = ss;
  __syncthreads();
  if (t == 0) {
    float tot = part[0] + part[1] + part[2] + part[3];
    invn[row] = 1.0f / fmaxf(sqrtf(tot), EPSf);
    D[row] = 0.f;
    if (row == 0) *accum = 0.f;
  }
}

// ---------------- Gram pass, fast path: fp8, BK=128 -----------------------
// 256 threads (4 waves, 2x2 grid; wave tile 64x64). LDS panel: 128 rows x
// 128 fp8 (128 B/row) -> BK=128, 8 K-steps. Physical 16B chunk p of row r
// holds logical chunk p ^ (r&7) (XOR applied on the per-lane GLOBAL source
// address; LDS dest linear, as global_load_lds requires).
// MFMA: f32_16x16x32_fp8_fp8 (A/B: row=l&15, k=(l>>4)*8+j; 8 B/lane).
__global__ __launch_bounds__(256) void k_gram_ldsdma(
    const unsigned char* __restrict__ xb, const float* __restrict__ invn,
    const int* __restrict__ y, const int* __restrict__ rank,
    float* __restrict__ D, float* __restrict__ S, int n, int d, int nb) {
  // bijective XCD-chunked remap (m204)
  int nwg = nb * (nb + 1) / 2;
  int q8 = nwg >> 3, r8 = nwg & 7;
  int xcd = blockIdx.x & 7, ridx = blockIdx.x >> 3;
  int bid = (xcd < r8 ? xcd * (q8 + 1) : r8 * (q8 + 1) + (xcd - r8) * q8) + ridx;

  // triangular decode: bid -> (by, bx) with by <= bx
  int by = 0, rowlen = nb, rem = bid;
  while (rem >= rowlen) { rem -= rowlen; ++by; --rowlen; }
  int bx = by + rem;
  int rowBase = by * TS, colBase = bx * TS;
  bool diag = (bx == by);

  __shared__ char ldsA[128 * 128];   // 16 KB
  __shared__ char ldsB[128 * 128];   // 16 KB
  __shared__ float ir_s[128], ic_s[128];
  __shared__ int yr_s[128], yc_s[128];
  __shared__ int rr_s[128], rc_s[128];

  int t = threadIdx.x;
  int lane = t & 63, wid = t >> 6;
  int wr = wid >> 1, wc = wid & 1;          // 2x2 wave grid, 64x64 per wave
  int l15 = lane & 15, l4 = lane >> 4;
  int lrow = lane >> 3, lp = lane & 7;      // staging: row-in-8 / 16B chunk

  if (t < 128) {
    ir_s[t] = invn[rowBase + t]; yr_s[t] = y[rowBase + t]; rr_s[t] = rank[rowBase + t];
    ic_s[t] = invn[colBase + t]; yc_s[t] = y[colBase + t]; rc_s[t] = rank[colBase + t];
  }

  f32x4 acc[4][4];
#pragma unroll
  for (int m = 0; m < 4; ++m)
#pragma unroll
    for (int nn = 0; nn < 4; ++nn) acc[m][nn] = (f32x4){0.f, 0.f, 0.f, 0.f};

  const char* ldsBr = diag ? ldsA : ldsB;
  int nt = d / 128;     // 8 K-steps

  for (int g = 0; g < nt; ++g) {
    __syncthreads();    // prev compute done: safe to overwrite panels
    // stage: 128 rows x 128 B; each wave-instr writes 1 KB = 8 rows.
#pragma unroll
    for (int j = 0; j < 4; ++j) {
      int seg = wid * 4 + j;                // 0..15, 8 rows each
      int row = seg * 8 + lrow;
      const unsigned char* srcA = xb + (size_t)(rowBase + row) * d + g * 128
                                  + ((lp ^ (row & 7)) << 4);
      __builtin_amdgcn_global_load_lds(
          (const __attribute__((address_space(1))) void*)srcA,
          (__attribute__((address_space(3))) void*)(ldsA + seg * 1024), 16, 0, 0);
    }
    if (!diag) {
#pragma unroll
      for (int j = 0; j < 4; ++j) {
        int seg = wid * 4 + j;
        int row = seg * 8 + lrow;
        const unsigned char* srcB = xb + (size_t)(colBase + row) * d + g * 128
                                    + ((lp ^ (row & 7)) << 4);
        __builtin_amdgcn_global_load_lds(
            (const __attribute__((address_space(1))) void*)srcB,
            (__attribute__((address_space(3))) void*)(ldsB + seg * 1024), 16, 0, 0);
      }
    }
    __syncthreads();    // drain: tile resident

#pragma unroll
    for (int kk = 0; kk < 4; ++kk) {        // 4 x K=32 per panel
      long a[4], b[4];
#pragma unroll
      for (int m = 0; m < 4; ++m) {
        int row = wr * 64 + m * 16 + l15;
        int slot = (kk * 2 + (l4 >> 1)) ^ (row & 7);
        a[m] = *(const long*)(ldsA + row * 128 + slot * 16 + (l4 & 1) * 8);
      }
#pragma unroll
      for (int nn = 0; nn < 4; ++nn) {
        int row = wc * 64 + nn * 16 + l15;
        int slot = (kk * 2 + (l4 >> 1)) ^ (row & 7);
        b[nn] = *(const long*)(ldsBr + row * 128 + slot * 16 + (l4 & 1) * 8);
      }
#pragma unroll
      for (int m = 0; m < 4; ++m)
#pragma unroll
        for (int nn = 0; nn < 4; ++nn)
          acc[m][nn] = __builtin_amdgcn_mfma_f32_16x16x32_fp8_fp8(a[m], b[nn], acc[m][nn], 0, 0, 0);
    }
  }

  // epilogue: C/D frag layout col=lane&15, row=(lane>>4)*4+r
  float cs[4] = {0.f, 0.f, 0.f, 0.f};
#pragma unroll
  for (int m = 0; m < 4; ++m) {
#pragma unroll
    for (int r = 0; r < 4; ++r) {
      int lr = wr * 64 + m * 16 + l4 * 4 + r;
      int gi = rowBase + lr;
      float ivr = ir_s[lr];
      int yi = yr_s[lr];
      float rs = 0.f;
#pragma unroll
      for (int nn = 0; nn < 4; ++nn) {
        int lc = wc * 64 + nn * 16 + l15;
        int gj = colBase + lc;
        float sim = acc[m][nn][r] * ivr * ic_s[lc];
        sim = fminf(fmaxf(sim, -1.0f + EPSf), 1.0f - EPSf);
        float s = fminf(__expf(sim * T_INV), 1e10f);
        if (yc_s[lc] != yi) {
          rs += s; cs[nn] += s;
        } else if (gi != gj) {
          S[(size_t)gi * MAXG + rc_s[lc]] = s;
          if (!diag) S[(size_t)gj * MAXG + rr_s[lr]] = s;
        }
      }
      rs += __shfl_xor(rs, 1, 64);
      rs += __shfl_xor(rs, 2, 64);
      rs += __shfl_xor(rs, 4, 64);
      rs += __shfl_xor(rs, 8, 64);
      if (l15 == 0) atomicAdd(&D[rowBase + lr], rs);
    }
  }
  if (!diag) {
#pragma unroll
    for (int nn = 0; nn < 4; ++nn) {
      float v = cs[nn];
      v += __shfl_xor(v, 16, 64);
      v += __shfl_xor(v, 32, 64);
      if (l4 == 0) atomicAdd(&D[colBase + wc * 64 + nn * 16 + l15], v);
    }
  }
}

// ---------------- Gram pass, fallback: reg-staged f32->bf16 ---------------
__global__ __launch_bounds__(256) void k_gram_reg(const float* __restrict__ x,
    const float* __restrict__ invn, const int* __restrict__ y,
    const int* __restrict__ rank, float* __restrict__ D, float* __restrict__ S,
    int n, int d, int nb) {
  int bid = blockIdx.x;
  int by = 0, rowlen = nb, rem = bid;
  while (rem >= rowlen) { rem -= rowlen; ++by; --rowlen; }
  int bx = by + rem;
  int rowBase = by * TS, colBase = bx * TS;
  bool diag = (bx == by);

  __shared__ char ldsA[128 * 128];
  __shared__ char ldsB[128 * 128];
  __shared__ float ir_s[128], ic_s[128];
  __shared__ int yr_s[128], yc_s[128];
  __shared__ int rr_s[128], rc_s[128];

  int t = threadIdx.x;
  int lane = t & 63, wid = t >> 6;
  int wr = wid >> 1, wc = wid & 1;
  int l15 = lane & 15, l4 = lane >> 4;

  if (t < 128) {
    ir_s[t] = invn[rowBase + t]; yr_s[t] = y[rowBase + t]; rr_s[t] = rank[rowBase + t];
    ic_s[t] = invn[colBase + t]; yc_s[t] = y[colBase + t]; rc_s[t] = rank[colBase + t];
  }

  f32x4 acc[4][4];
#pragma unroll
  for (int m = 0; m < 4; ++m)
#pragma unroll
    for (int nn = 0; nn < 4; ++nn) acc[m][nn] = (f32x4){0.f, 0.f, 0.f, 0.f};

  const char* ldsBr = diag ? ldsA : ldsB;

  for (int k0 = 0; k0 < d; k0 += 64) {
    __syncthreads();
#pragma unroll
    for (int i = 0; i < 8; ++i) {
      int c = t + i * 256;
      int row = c >> 4, fc = c & 15;
      float4 v = *(const float4*)(x + (size_t)(rowBase + row) * d + k0 + fc * 4);
      ushort4 h;
      h.x = f2bf(v.x); h.y = f2bf(v.y); h.z = f2bf(v.z); h.w = f2bf(v.w);
      int off = row * 128 + ((((fc >> 1) ^ (row & 7))) << 4) + (fc & 1) * 8;
      *(ushort4*)(ldsA + off) = h;
    }
    if (!diag) {
#pragma unroll
      for (int i = 0; i < 8; ++i) {
        int c = t + i * 256;
        int row = c >> 4, fc = c & 15;
        float4 v = *(const float4*)(x + (size_t)(colBase + row) * d + k0 + fc * 4);
        ushort4 h;
        h.x = f2bf(v.x); h.y = f2bf(v.y); h.z = f2bf(v.z); h.w = f2bf(v.w);
        int off = row * 128 + ((((fc >> 1) ^ (row & 7))) << 4) + (fc & 1) * 8;
        *(ushort4*)(ldsB + off) = h;
      }
    }
    __syncthreads();

#pragma unroll
    for (int kk = 0; kk < 2; ++kk) {
      bf16x8 a[4], b[4];
#pragma unroll
      for (int m = 0; m < 4; ++m) {
        int row = wr * 64 + m * 16 + l15;
        int slot = (kk * 4 + l4) ^ (row & 7);
        a[m] = *(const bf16x8*)(ldsA + row * 128 + slot * 16);
      }
#pragma unroll
      for (int nn = 0; nn < 4; ++nn) {
        int row = wc * 64 + nn * 16 + l15;
        int slot = (kk * 4 + l4) ^ (row & 7);
        b[nn] = *(const bf16x8*)(ldsBr + row * 128 + slot * 16);
      }
#pragma unroll
      for (int m = 0; m < 4; ++m)
#pragma unroll
        for (int nn = 0; nn < 4; ++nn)
          acc[m][nn] = __builtin_amdgcn_mfma_f32_16x16x32_bf16(a[m], b[nn], acc[m][nn], 0, 0, 0);
    }
  }

  float cs[4] = {0.f, 0.f, 0.f, 0.f};
#pragma unroll
  for (int m = 0; m < 4; ++m) {
#pragma unroll
    for (int r = 0; r < 4; ++r) {
      int lr = wr * 64 + m * 16 + l4 * 4 + r;
      int gi = rowBase + lr;
      float ivr = ir_s[lr];
      int yi = yr_s[lr];
      float rs = 0.f;
#pragma unroll
      for (int nn = 0; nn < 4; ++nn) {
        int lc = wc * 64 + nn * 16 + l15;
        int gj = colBase + lc;
        float sim = acc[m][nn][r] * ivr * ic_s[lc];
        sim = fminf(fmaxf(sim, -1.0f + EPSf), 1.0f - EPSf);
        float s = fminf(__expf(sim * T_INV), 1e10f);
        if (yc_s[lc] != yi) {
          rs += s; cs[nn] += s;
        } else if (S && gi != gj) {
          S[(size_t)gi * MAXG + rc_s[lc]] = s;
          if (!diag) S[(size_t)gj * MAXG + rr_s[lr]] = s;
        }
      }
      rs += __shfl_xor(rs, 1, 64);
      rs += __shfl_xor(rs, 2, 64);
      rs += __shfl_xor(rs, 4, 64);
      rs += __shfl_xor(rs, 8, 64);
      if (l15 == 0) atomicAdd(&D[rowBase + lr], rs);
    }
  }
  if (!diag) {
#pragma unroll
    for (int nn = 0; nn < 4; ++nn) {
      float v = cs[nn];
      v += __shfl_xor(v, 16, 64);
      v += __shfl_xor(v, 32, 64);
      if (l4 == 0) atomicAdd(&D[colBase + wc * 64 + nn * 16 + l15], v);
    }
  }
}

// Pass B (fast): grid-strided; per-block partial sums, no global atomics.
__global__ __launch_bounds__(256) void k_loss2(const int* __restrict__ y,
    const int* __restrict__ offs, const int* __restrict__ rows,
    const float* __restrict__ D, const float* __restrict__ S,
    float* __restrict__ partials, int n) {
  int t = threadIdx.x;
  int total = n * MAXG;
  float sum = 0.f;
  for (int gid = blockIdx.x * 256 + t; gid < total; gid += gridDim.x * 256) {
    int i = gid >> 7;          // MAXG = 128
    int slot = gid & (MAXG - 1);
    int g = y[i];
    int start = offs[g], cnt = offs[g + 1] - start;
    if (slot < cnt) {
      int j = rows[start + slot];
      if (j != i) {
        float s = S[(size_t)i * MAXG + slot];
        sum += logf(s + D[i] + EPSf) - logf(s);
      }
    }
  }
  sum = wave_reduce_sum64(sum);
  __shared__ float part[4];
  int lane = t & 63, wid = t >> 6;
  if (lane == 0) part[wid] = sum;
  __syncthreads();
  if (t == 0) partials[blockIdx.x] = part[0] + part[1] + part[2] + part[3];
}

// Pass B (fallback): recompute dots for same-label pairs
__global__ __launch_bounds__(256) void k_loss(const float* __restrict__ x,
    const float* __restrict__ invn, const int* __restrict__ y,
    const int* __restrict__ offs, const int* __restrict__ rows,
    const float* __restrict__ D, float* __restrict__ accum, int n, int d) {
  int i = blockIdx.x;
  int t = threadIdx.x, lane = t & 63, wid = t >> 6;
  __shared__ float4 xi4[256];
  __shared__ float wpart[4];

  const float4* xr = (const float4*)(x + (size_t)i * d);
  for (int q = t; q < d / 4; q += 256) xi4[q] = xr[q];
  __syncthreads();

  int g = y[i];
  int start = offs[g], end = offs[g + 1];
  float invi = invn[i];
  float Di = D[i];
  float wsum = 0.f;

  for (int idx = start + wid; idx < end; idx += 4) {
    int j = rows[idx];
    if (j == i) continue;
    const float4* xj = (const float4*)(x + (size_t)j * d);
    float acc = 0.f;
#pragma unroll 4
    for (int q = 0; q < d / 256; ++q) {
      float4 vj = xj[lane + 64 * q];
      float4 vi = xi4[lane + 64 * q];
      acc = fmaf(vj.x, vi.x, acc);
      acc = fmaf(vj.y, vi.y, acc);
      acc = fmaf(vj.z, vi.z, acc);
      acc = fmaf(vj.w, vi.w, acc);
    }
    acc = wave_reduce_sum64(acc);
    if (lane == 0) {
      float sim = acc * invi * invn[j];
      sim = fminf(fmaxf(sim, -1.0f + EPSf), 1.0f - EPSf);
      float s = fminf(expf(sim * T_INV), 1e10f);
      wsum += logf(s + Di + EPSf) - logf(s);
    }
  }

  if (lane == 0) wpart[wid] = wsum;
  __syncthreads();
  if (t == 0) atomicAdd(accum, wpart[0] + wpart[1] + wpart[2] + wpart[3]);
}

// Final reduce: sums `cnt` partials, writes out/(2n).
__global__ __launch_bounds__(256) void k_final(const float* __restrict__ partials,
    int cnt, float* __restrict__ out, int out_size, int n) {
  int t = threadIdx.x;
  float s = 0.f;
  for (int i = t; i < cnt; i += 256) s += partials[i];
  s = wave_reduce_sum64(s);
  __shared__ float part[4];
  int lane = t & 63, wid = t >> 6;
  if (lane == 0) part[wid] = s;
  __syncthreads();
  if (t == 0) {
    float v = part[0] + part[1] + part[2] + part[3];
    for (int k = 0; k < out_size; ++k) out[k] = v / (2.0f * n);
  }
}

extern "C" void kernel_launch(void* const* d_in, const int* in_sizes, int n_in,
                              void* d_out, int out_size, void* d_ws, size_t ws_size,
                              hipStream_t stream) {
  const float* x = (const float*)d_in[0];
  const int*   y = (const int*)d_in[1];
  int n = in_sizes[1];
  int d = in_sizes[0] / n;

  char* ws = (char*)d_ws;
  float* invn     = (float*)(ws);            // 16 KB
  float* D        = (float*)(ws + 16384);    // 16 KB
  int*   offs     = (int*)(ws + 32768);      // 129 ints (pad to 2 KB)
  int*   rows     = (int*)(ws + 34816);      // 16 KB
  int*   rank     = (int*)(ws + 51200);      // 16 KB
  float* accum    = (float*)(ws + 67584);    // 4 B (pad 256 B)
  float* partials = (float*)(ws + 67840);    // LBLK floats (2 KB)
  float* S        = (float*)(ws + 69888);    // n*MAXG*4 = 2 MB
  size_t xb_off = 69888 + (size_t)n * MAXG * 4;
  xb_off = (xb_off + 255) & ~(size_t)255;
  unsigned char* xb = (unsigned char*)(ws + xb_off);   // n*d fp8 = 4 MB

  bool hasS  = ws_size >= 69888 + (size_t)n * MAXG * 4;
  bool hasXb = hasS && ws_size >= xb_off + (size_t)n * d && (d % 128 == 0);

  k_prep<<<n + 1, 256, 0, stream>>>(x, y, invn, D, hasXb ? xb : nullptr,
                                    accum, offs, rows, rank, n, d);

  int nb = n / TS;
  int nblocks = nb * (nb + 1) / 2;
  if (hasXb) {
    k_gram_ldsdma<<<nblocks, 256, 0, stream>>>(xb, invn, y, rank, D, S, n, d, nb);
  } else {
    k_gram_reg<<<nblocks, 256, 0, stream>>>(x, invn, y, rank, D, hasS ? S : nullptr, n, d, nb);
  }
  if (hasS) {
    k_loss2<<<LBLK, 256, 0, stream>>>(y, offs, rows, D, S, partials, n);
    k_final<<<1, 256, 0, stream>>>(partials, LBLK, (float*)d_out, out_size, n);
  } else {
    k_loss<<<n, 256, 0, stream>>>(x, invn, y, offs, rows, D, accum, n, d);
    k_final<<<1, 256, 0, stream>>>(accum, 1, (float*)d_out, out_size, n);
  }
}